// Round 4
// baseline (2235.449 us; speedup 1.0000x reference)
//
#include <hip/hip_runtime.h>
#include <math.h>

#define NB 262144
#define ND 128
#define NL 8

typedef __bf16 bf16x8 __attribute__((ext_vector_type(8)));
typedef float  f32x4  __attribute__((ext_vector_type(4)));

union BFP { unsigned int u; __bf16 h[2]; unsigned short s[2]; };

__device__ __forceinline__ float sigm(float x){ return 1.0f/(1.0f + __expf(-x)); }
__device__ __forceinline__ float tanhfast(float x){
  float t = __expf(-2.0f*fabsf(x));
  return copysignf((1.0f - t)/(1.0f + t), x);
}
// 16-lane sum via DPP: quad_perm xor1, xor2, row_ror:4, row_ror:8 — no LDS pipe
template<int CTRL>
__device__ __forceinline__ float dppadd(float v){
  int y = __builtin_amdgcn_update_dpp(0, __builtin_bit_cast(int, v), CTRL, 0xf, 0xf, true);
  return v + __builtin_bit_cast(float, y);
}
__device__ __forceinline__ float red16(float v){
  v = dppadd<0xB1>(v);   // quad_perm [1,0,3,2]  (xor 1)
  v = dppadd<0x4E>(v);   // quad_perm [2,3,0,1]  (xor 2)
  v = dppadd<0x124>(v);  // row_ror:4
  v = dppadd<0x128>(v);  // row_ror:8
  return v;
}
__device__ __forceinline__ unsigned short bfbits(float f){
  BFP x; x.h[0] = (__bf16)f; return x.s[0];
}
__device__ __forceinline__ unsigned int pk2(float a, float b){
  BFP x; x.h[0]=(__bf16)a; x.h[1]=(__bf16)b; return x.u;
}

// ---- prep 1: repack Wg/Wp (fp32, [L][256][128]) into bf16 B-fragment order ----
// dst layout: [(l*2+mat)][kf(8)][cf(8)][lane(64)] x 16B ; mat 0 = Wg, 1 = Wp
__global__ void repack_w(const float* __restrict__ Wp, const float* __restrict__ Wg,
                         uint4* __restrict__ dst){
  int t = blockIdx.x*256 + threadIdx.x;      // 65536 threads
  int lane = t & 63;
  int frag = t >> 6;                          // 1024 frags
  int cf = frag & 7, kf = (frag >> 3) & 7, mat = (frag >> 6) & 1, l = frag >> 7;
  const float* W = mat ? Wp : Wg;
  int k = kf*32 + (lane >> 4)*8;
  int n = cf*16 + (lane & 15);
  const float* src = W + (l*256 + k)*ND + n;
  bf16x8 v;
#pragma unroll
  for (int j=0;j<8;++j) v[j] = (__bf16)src[j*ND];
  dst[((l*2 + mat)*64 + kf*8 + cf)*64 + lane] = __builtin_bit_cast(uint4, v);
}

// ---- prep 2: pdot[row][l] = previous[row] . Ws_l[128:256] + bs_l (fp32) ----
__global__ void prevdot_k(const float* __restrict__ previous, const float* __restrict__ Ws,
                          const float* __restrict__ bs, float* __restrict__ pdot){
  int t = blockIdx.x*256 + threadIdx.x;
  int row = t >> 4, g = t & 15;
  const float* p = previous + (size_t)row*ND + g*8;
  float4 a = *(const float4*)p;
  float4 b = *(const float4*)(p+4);
#pragma unroll
  for (int l=0;l<NL;++l){
    const float* w = Ws + l*256 + 128 + g*8;
    float s = a.x*w[0] + a.y*w[1] + a.z*w[2] + a.w*w[3]
            + b.x*w[4] + b.y*w[5] + b.z*w[6] + b.w*w[7];
    s += __shfl_xor(s,1); s += __shfl_xor(s,2); s += __shfl_xor(s,4); s += __shfl_xor(s,8);
    if (g==0) pdot[row*NL + l] = s + bs[l];
  }
}

// ---- main fused kernel: 256 threads, 4 waves x 16 rows, barrier-free ----
// B-fragments are read straight from L2 (weights = 1MB, fully L2-resident);
// the only LDS is a 16KB wave-private transpose tile -> zero __syncthreads.
__global__ __launch_bounds__(256, 2)
void fused_k(const float* __restrict__ signal, const float* __restrict__ previous,
             const float* __restrict__ bp, const float* __restrict__ bg,
             const float* __restrict__ Ws, const float* __restrict__ gamma,
             const float* __restrict__ beta,
             const uint4* __restrict__ wpk, const float* __restrict__ pdot,
             float* __restrict__ out)
{
  __shared__ unsigned short tile[64*128];    // 16KB: current tile, bf16, XOR-swizzled, wave-private rows

  const int tid  = threadIdx.x;
  const int w    = tid >> 6;
  const int lane = tid & 63;
  const int llo  = lane & 15;
  const int lhi  = lane >> 4;
  const int rbase = w * 16;
  const int row0  = blockIdx.x * 64;

  // previous half of joined, as persistent A-fragments (K slots 128..255)
  bf16x8 prevA[4];
  {
    int row = row0 + rbase + llo;
#pragma unroll
    for (int kf=0; kf<4; ++kf){
      const float* p = previous + (size_t)row*ND + kf*32 + lhi*8;
      float4 f0 = *(const float4*)p;
      float4 f1 = *(const float4*)(p+4);
      bf16x8 v;
      v[0]=(__bf16)f0.x; v[1]=(__bf16)f0.y; v[2]=(__bf16)f0.z; v[3]=(__bf16)f0.w;
      v[4]=(__bf16)f1.x; v[5]=(__bf16)f1.y; v[6]=(__bf16)f1.z; v[7]=(__bf16)f1.w;
      prevA[kf] = v;
    }
  }

  float curC[8][4];           // current, C-layout, fp32 master
  f32x4 accv[8];              // accumulated output
  float active[4], depth[4], smass[4], gsum[4], dsum[4], asum[4];
#pragma unroll
  for (int cf=0; cf<8; ++cf){
    accv[cf] = (f32x4){0.f,0.f,0.f,0.f};
#pragma unroll
    for (int r=0; r<4; ++r){
      int row = row0 + rbase + lhi*4 + r;
      curC[cf][r] = signal[(size_t)row*ND + cf*16 + llo];
    }
  }
#pragma unroll
  for (int r=0; r<4; ++r){
    active[r]=1.f; depth[r]=0.f; smass[r]=0.f;
    gsum[r]=0.f; dsum[r]=0.f; asum[r]=0.f;
  }

#pragma unroll 1
  for (int l=0; l<NL; ++l){
    // write current into tile (bf16, swizzled: byte ^= (row&7)<<4) — wave-private rows
#pragma unroll
    for (int cf=0; cf<8; ++cf)
#pragma unroll
      for (int r=0; r<4; ++r){
        int rowl = rbase + lhi*4 + r;
        int byte = ((cf*16 + llo)*2) ^ ((rowl & 7) << 4);
        tile[rowl*128 + (byte>>1)] = bfbits(curC[cf][r]);
      }
    // wave-local write->read coherence (same wave owns these 16 rows)
    asm volatile("s_waitcnt lgkmcnt(0)" ::: "memory");
    __builtin_amdgcn_sched_barrier(0);
    bf16x8 curA[4];
    {
      int rowl = rbase + llo;
      const char* base = (const char*)tile + rowl*256;
      int sw = (rowl & 7) << 4;
#pragma unroll
      for (int kf=0; kf<4; ++kf){
        int byte = (kf*64 + lhi*16) ^ sw;
        curA[kf] = __builtin_bit_cast(bf16x8, *(const uint4*)(base + byte));
      }
    }

    f32x4 pacc[8];
    auto zero_acc = [&](){
#pragma unroll
      for (int cf=0; cf<8; ++cf) pacc[cf] = (f32x4){0.f,0.f,0.f,0.f};
    };
    // B-fragments straight from global (L2-resident packed weights)
    auto run_gemm = [&](int mat){
      const uint4* gB = wpk + (size_t)(l*2 + mat)*4096 + lane;
#pragma unroll
      for (int kf=0; kf<4; ++kf){
        bf16x8 a = curA[kf];
#pragma unroll
        for (int cf=0; cf<8; ++cf){
          bf16x8 b = __builtin_bit_cast(bf16x8, gB[(kf*8+cf)*64]);
          pacc[cf] = __builtin_amdgcn_mfma_f32_16x16x32_bf16(a, b, pacc[cf], 0,0,0);
        }
      }
#pragma unroll
      for (int kp=0; kp<4; ++kp){
        bf16x8 a = prevA[kp];
#pragma unroll
        for (int cf=0; cf<8; ++cf){
          bf16x8 b = __builtin_bit_cast(bf16x8, gB[((kp+4)*8+cf)*64]);
          pacc[cf] = __builtin_amdgcn_mfma_f32_16x16x32_bf16(a, b, pacc[cf], 0,0,0);
        }
      }
    };

    // ---- gate GEMM ----
    zero_acc();
    run_gemm(0);

    // ---- gate elementwise ----
    unsigned int gstash[8][2];
    {
      float gpart[4] = {0.f,0.f,0.f,0.f};
#pragma unroll
      for (int cf=0; cf<8; ++cf){
        float bgv = bg[l*ND + cf*16 + llo];
        float g0 = sigm(pacc[cf][0] + bgv);
        float g1 = sigm(pacc[cf][1] + bgv);
        float g2 = sigm(pacc[cf][2] + bgv);
        float g3 = sigm(pacc[cf][3] + bgv);
        gpart[0]+=g0; gpart[1]+=g1; gpart[2]+=g2; gpart[3]+=g3;
        gstash[cf][0] = pk2(g0,g1);
        gstash[cf][1] = pk2(g2,g3);
      }
#pragma unroll
      for (int r=0; r<4; ++r)
        gsum[r] += red16(gpart[r]) * (1.0f/ND);
    }

    // ---- candidate GEMM ----
    zero_acc();
    run_gemm(1);

    // ---- elementwise update + LN + stats (pure register work) ----
    float s1[4] = {0.f,0.f,0.f,0.f};
    float s2[4] = {0.f,0.f,0.f,0.f};
#pragma unroll
    for (int cf=0; cf<8; ++cf){
      float bpv = bp[l*ND + cf*16 + llo];
#pragma unroll
      for (int r=0; r<4; ++r){
        float cand = tanhfast(pacc[cf][r] + bpv);
        float c = curC[cf][r];
        BFP gp; gp.u = gstash[cf][r>>1];
        float g = (float)gp.h[r&1];
        float x = c + g*(cand - c);
        pacc[cf][r] = x;
        s1[r] += x; s2[r] += x*x;
      }
    }
    float mu[4], inv[4];
#pragma unroll
    for (int r=0; r<4; ++r){
      float m = red16(s1[r]) * (1.0f/ND);
      float q = red16(s2[r]) * (1.0f/ND);
      mu[r] = m;
      inv[r] = rsqrtf(q - m*m + 1e-5f);
    }
    float dpart[4] = {0.f,0.f,0.f,0.f};
    float apart[4] = {0.f,0.f,0.f,0.f};
#pragma unroll
    for (int cf=0; cf<8; ++cf){
      float gm = gamma[l*ND + cf*16 + llo];
      float bt = beta [l*ND + cf*16 + llo];
      float wv = Ws[l*256 + cf*16 + llo];
#pragma unroll
      for (int r=0; r<4; ++r){
        float un = (pacc[cf][r] - mu[r])*inv[r]*gm + bt;
        float c = curC[cf][r];
        float df = un - c;
        dpart[r] += df*df;
        apart[r] += un*wv;
        pacc[cf][r] = un;
      }
    }
    float smrow[4];
#pragma unroll
    for (int r=0; r<4; ++r){
      float dd = red16(dpart[r]);
      float av = red16(apart[r]);
      int row = row0 + rbase + lhi*4 + r;
      float adq = sigm(av + pdot[row*NL + l]);
      float sp  = sigm((adq - 0.6f)*10.0f);
      float sm  = active[r]*sp;
      asum[r] += adq;
      dsum[r] += sqrtf(dd);
      depth[r] += sm * (float)(l+1);
      smass[r] += sm;
      active[r] *= (1.0f - sp);
      smrow[r] = sm;
    }
#pragma unroll
    for (int cf=0; cf<8; ++cf)
#pragma unroll
      for (int r=0; r<4; ++r){
        float un = pacc[cf][r];
        accv[cf][r] += smrow[r]*un;
        curC[cf][r] = un;
      }
  }

  // ---- outputs ----
#pragma unroll
  for (int cf=0; cf<8; ++cf)
#pragma unroll
    for (int r=0; r<4; ++r){
      int row = row0 + rbase + lhi*4 + r;
      out[(size_t)row*ND + cf*16 + llo] = accv[cf][r] + active[r]*curC[cf][r];
    }
  if (llo == 0){
    const size_t BD = (size_t)NB*ND;
#pragma unroll
    for (int r=0; r<4; ++r){
      int row = row0 + rbase + lhi*4 + r;
      out[BD + row]                = gsum[r]*(1.0f/NL);
      out[BD + NB + row]           = dsum[r]*(1.0f/NL);
      out[BD + 2*(size_t)NB + row] = depth[r] + active[r]*(float)NL;
      out[BD + 3*(size_t)NB + row] = smass[r];
      out[BD + 4*(size_t)NB + row] = asum[r]*(1.0f/NL);
    }
  }
}

extern "C" void kernel_launch(void* const* d_in, const int* in_sizes, int n_in,
                              void* d_out, int out_size, void* d_ws, size_t ws_size,
                              hipStream_t stream){
  const float* signal   = (const float*)d_in[0];
  const float* previous = (const float*)d_in[1];
  const float* Wp    = (const float*)d_in[2];
  const float* bp    = (const float*)d_in[3];
  const float* Wg    = (const float*)d_in[4];
  const float* bg    = (const float*)d_in[5];
  const float* Ws    = (const float*)d_in[6];
  const float* bs    = (const float*)d_in[7];
  const float* gamma = (const float*)d_in[8];
  const float* beta  = (const float*)d_in[9];

  uint4* wpk  = (uint4*)d_ws;                                   // 1 MB packed weights
  float* pdot = (float*)((char*)d_ws + (size_t)NL*2*65536);     // 8 MB prevdot

  repack_w<<<256, 256, 0, stream>>>(Wp, Wg, wpk);
  prevdot_k<<<NB/16, 256, 0, stream>>>(previous, Ws, bs, pdot);
  fused_k<<<NB/64, 256, 0, stream>>>(signal, previous, bp, bg, Ws, gamma, beta,
                                     wpk, pdot, (float*)d_out);
}

// Round 5
// 1365.171 us; speedup vs baseline: 1.6375x; 1.6375x over previous
//
#include <hip/hip_runtime.h>
#include <math.h>

#define NB 262144
#define ND 128
#define NL 8

typedef __bf16 bf16x8 __attribute__((ext_vector_type(8)));
typedef float  f32x4  __attribute__((ext_vector_type(4)));

union BFP { unsigned int u; __bf16 h[2]; unsigned short s[2]; };
union F4  { float4 f; float a[4]; };

__device__ __forceinline__ float sigm(float x){ return 1.0f/(1.0f + __expf(-x)); }
__device__ __forceinline__ float tanhfast(float x){
  float t = __expf(-2.0f*fabsf(x));
  return copysignf((1.0f - t)/(1.0f + t), x);
}
// row-reduction: row r lives in lanes {r, r+16, r+32, r+48}
__device__ __forceinline__ float redrow(float v){
  v += __shfl_xor(v, 16);
  v += __shfl_xor(v, 32);
  return v;
}
__device__ __forceinline__ unsigned int pk2(float a, float b){
  BFP x; x.h[0]=(__bf16)a; x.h[1]=(__bf16)b; return x.u;
}
__device__ __forceinline__ float ubf(unsigned int u, int hi){
  BFP x; x.u = u; return (float)x.h[hi];
}
__device__ __forceinline__ void gload16(const void* g, void* s){
  __builtin_amdgcn_global_load_lds((const __attribute__((address_space(1))) unsigned int*)g,
                                   (__attribute__((address_space(3))) unsigned int*)s,
                                   16, 0, 0);
}

// ---- prep 1: repack Wg/Wp (fp32, [L][256][128]) into bf16 A-operand fragment order ----
// dst: [(l*2+mat)][kf(8)][cf(8)][lane(64)] x 16B ; mat 0 = Wg, 1 = Wp
// frag: n = cf*16 + (lane&15), k = kf*32 + (lane>>4)*8 + j
__global__ void repack_w(const float* __restrict__ Wp, const float* __restrict__ Wg,
                         uint4* __restrict__ dst){
  int t = blockIdx.x*256 + threadIdx.x;      // 65536 threads
  int lane = t & 63;
  int frag = t >> 6;                          // 1024 frags
  int cf = frag & 7, kf = (frag >> 3) & 7, mat = (frag >> 6) & 1, l = frag >> 7;
  const float* W = mat ? Wp : Wg;
  int k = kf*32 + (lane >> 4)*8;
  int n = cf*16 + (lane & 15);
  const float* src = W + (l*256 + k)*ND + n;
  bf16x8 v;
#pragma unroll
  for (int j=0;j<8;++j) v[j] = (__bf16)src[j*ND];
  dst[((l*2 + mat)*64 + kf*8 + cf)*64 + lane] = __builtin_bit_cast(uint4, v);
}

// ---- prep 2: pdot[row][l] = previous[row] . Ws_l[128:256] + bs_l (fp32) ----
__global__ void prevdot_k(const float* __restrict__ previous, const float* __restrict__ Ws,
                          const float* __restrict__ bs, float* __restrict__ pdot){
  int t = blockIdx.x*256 + threadIdx.x;
  int row = t >> 4, g = t & 15;
  const float* p = previous + (size_t)row*ND + g*8;
  float4 a = *(const float4*)p;
  float4 b = *(const float4*)(p+4);
#pragma unroll
  for (int l=0;l<NL;++l){
    const float* w = Ws + l*256 + 128 + g*8;
    float s = a.x*w[0] + a.y*w[1] + a.z*w[2] + a.w*w[3]
            + b.x*w[4] + b.y*w[5] + b.z*w[6] + b.w*w[7];
    s += __shfl_xor(s,1); s += __shfl_xor(s,2); s += __shfl_xor(s,4); s += __shfl_xor(s,8);
    if (g==0) pdot[row*NL + l] = s + bs[l];
  }
}

// ---- main fused kernel: 256 threads, 4 waves x 32 rows (swapped-operand MFMA) ----
// Joined tile [128 rows][256 feats] bf16 (64KB): cur half rewritten per level,
// prev half written once. Weights stream through 2x8KB ping-pong LDS stages.
__global__ __launch_bounds__(256, 2)
void fused_k(const float* __restrict__ signal, const float* __restrict__ previous,
             const float* __restrict__ bp, const float* __restrict__ bg,
             const float* __restrict__ Ws, const float* __restrict__ gamma,
             const float* __restrict__ beta,
             const uint4* __restrict__ wpk, const float* __restrict__ pdot,
             float* __restrict__ out)
{
  __shared__ unsigned short tile[128*256];   // 64KB joined [row][feat], XOR-swizzled
  __shared__ uint4 wbuf[2][512];             // 2 x 8KB weight stages (1 kf x 8 cf)

  const int tid  = threadIdx.x;
  const int w    = tid >> 6;
  const int lane = tid & 63;
  const int llo  = lane & 15;
  const int lhi  = lane >> 4;
  const int rbase = w * 32;
  const int row0  = blockIdx.x * 128;
  const int swz   = (llo & 7) << 4;

  auto gstage = [&](int s, int b){
    const char* src = (const char*)wpk + (size_t)s*8192;
    char* d = (char*)&wbuf[b][0];
    gload16(src + tid*16, d + tid*16);
    gload16(src + 4096 + tid*16, d + 4096 + tid*16);
  };

  // prologue: start staging level0/Wg/kf0 immediately
  gstage(0, 0);

  // per-lane state: rows r(g) = row0 + rbase + g*16 + llo ; feats n = 16cf+4lhi+j
  unsigned int curD[2][16];     // current, bf16 packed at D positions
  unsigned int gstash[2][16];   // gate, bf16 packed
  float accv[2][8][4];          // accumulated output (f32)
  f32x4 pacc[2][8];             // MFMA accumulators
  float active[2], depth[2], smass[2], gsum[2], dsum[2], asum[2];

#pragma unroll
  for (int g=0; g<2; ++g){
    int rl = rbase + g*16 + llo;
    int rowg = row0 + rl;
    // signal -> curD + tile cur half
#pragma unroll
    for (int cf=0; cf<8; ++cf){
      F4 v; v.f = *(const float4*)&signal[(size_t)rowg*ND + 16*cf + 4*lhi];
      unsigned p0 = pk2(v.a[0], v.a[1]);
      unsigned p1 = pk2(v.a[2], v.a[3]);
      curD[g][2*cf]   = p0;
      curD[g][2*cf+1] = p1;
      char* dst = (char*)tile + rl*512 + ((32*cf + 8*lhi) ^ swz);
      *(unsigned long long*)dst = (unsigned long long)p0 | ((unsigned long long)p1 << 32);
      pacc[g][cf] = (f32x4){0.f,0.f,0.f,0.f};
#pragma unroll
      for (int j=0;j<4;++j) accv[g][cf][j] = 0.f;
    }
    // previous -> tile prev half (feats 128..255), written once
#pragma unroll
    for (int kfp=0; kfp<4; ++kfp){
      const float* p = previous + (size_t)rowg*ND + kfp*32 + lhi*8;
      F4 a; a.f = *(const float4*)p;
      F4 b; b.f = *(const float4*)(p+4);
      uint4 pv;
      pv.x = pk2(a.a[0], a.a[1]);
      pv.y = pk2(a.a[2], a.a[3]);
      pv.z = pk2(b.a[0], b.a[1]);
      pv.w = pk2(b.a[2], b.a[3]);
      char* dst = (char*)tile + rl*512 + ((256 + 64*kfp + 16*lhi) ^ swz);
      *(uint4*)dst = pv;
    }
    active[g]=1.f; depth[g]=0.f; smass[g]=0.f; gsum[g]=0.f; dsum[g]=0.f; asum[g]=0.f;
  }

  auto compute = [&](int s){
    int kf  = s & 7;
    int buf = s & 1;
    int off = (64*kf + 16*lhi) ^ swz;
    const char* tb = (const char*)tile;
    bf16x8 xf0 = __builtin_bit_cast(bf16x8, *(const uint4*)(tb + (rbase      + llo)*512 + off));
    bf16x8 xf1 = __builtin_bit_cast(bf16x8, *(const uint4*)(tb + (rbase + 16 + llo)*512 + off));
    const uint4* wb = &wbuf[buf][lane];
#pragma unroll
    for (int cf=0; cf<8; ++cf){
      bf16x8 wf = __builtin_bit_cast(bf16x8, wb[cf*64]);
      pacc[0][cf] = __builtin_amdgcn_mfma_f32_16x16x32_bf16(wf, xf0, pacc[0][cf], 0,0,0);
      pacc[1][cf] = __builtin_amdgcn_mfma_f32_16x16x32_bf16(wf, xf1, pacc[1][cf], 0,0,0);
    }
  };

  auto gate_epi = [&](int lev){
#pragma unroll
    for (int g=0; g<2; ++g){
      float gp = 0.f;
#pragma unroll
      for (int cf=0; cf<8; ++cf){
        F4 bgv; bgv.f = *(const float4*)&bg[lev*ND + 16*cf + 4*lhi];
        float g0 = sigm(pacc[g][cf][0] + bgv.a[0]);
        float g1 = sigm(pacc[g][cf][1] + bgv.a[1]);
        float g2 = sigm(pacc[g][cf][2] + bgv.a[2]);
        float g3 = sigm(pacc[g][cf][3] + bgv.a[3]);
        gp += g0 + g1 + g2 + g3;
        gstash[g][2*cf]   = pk2(g0, g1);
        gstash[g][2*cf+1] = pk2(g2, g3);
        pacc[g][cf] = (f32x4){0.f,0.f,0.f,0.f};
      }
      gsum[g] += redrow(gp) * (1.0f/ND);
    }
  };

  auto cand_epi = [&](int lev, bool wrtile){
#pragma unroll
    for (int g=0; g<2; ++g){
      int rl = rbase + g*16 + llo;
      int rowg = row0 + rl;
      float s1 = 0.f, s2 = 0.f;
#pragma unroll
      for (int cf=0; cf<8; ++cf){
        F4 bpv; bpv.f = *(const float4*)&bp[lev*ND + 16*cf + 4*lhi];
#pragma unroll
        for (int j=0;j<4;++j){
          float cand = tanhfast(pacc[g][cf][j] + bpv.a[j]);
          float c  = ubf(curD[g][2*cf + (j>>1)], j&1);
          float gt = ubf(gstash[g][2*cf + (j>>1)], j&1);
          float x = c + gt*(cand - c);
          pacc[g][cf][j] = x;
          s1 += x; s2 += x*x;
        }
      }
      s1 = redrow(s1); s2 = redrow(s2);
      float mu  = s1*(1.0f/ND);
      float inv = rsqrtf(s2*(1.0f/ND) - mu*mu + 1e-5f);
      float dp = 0.f, ap = 0.f;
#pragma unroll
      for (int cf=0; cf<8; ++cf){
        F4 gm; gm.f = *(const float4*)&gamma[lev*ND + 16*cf + 4*lhi];
        F4 bt; bt.f = *(const float4*)&beta [lev*ND + 16*cf + 4*lhi];
        F4 wv; wv.f = *(const float4*)&Ws   [lev*2*ND + 16*cf + 4*lhi];
#pragma unroll
        for (int j=0;j<4;++j){
          float un = (pacc[g][cf][j] - mu)*inv*gm.a[j] + bt.a[j];
          float c  = ubf(curD[g][2*cf + (j>>1)], j&1);
          float df = un - c;
          dp += df*df;
          ap += un*wv.a[j];
          pacc[g][cf][j] = un;
        }
      }
      dp = redrow(dp); ap = redrow(ap);
      float adq = sigm(ap + pdot[(size_t)rowg*NL + lev]);
      float sp  = sigm((adq - 0.6f)*10.0f);
      float sm  = active[g]*sp;
      asum[g] += adq;
      dsum[g] += sqrtf(dp);
      depth[g] += sm * (float)(lev+1);
      smass[g] += sm;
      active[g] *= (1.0f - sp);
#pragma unroll
      for (int cf=0; cf<8; ++cf){
#pragma unroll
        for (int j=0;j<4;++j) accv[g][cf][j] += sm * pacc[g][cf][j];
        unsigned p0 = pk2(pacc[g][cf][0], pacc[g][cf][1]);
        unsigned p1 = pk2(pacc[g][cf][2], pacc[g][cf][3]);
        curD[g][2*cf]   = p0;
        curD[g][2*cf+1] = p1;
        if (wrtile){
          char* dst = (char*)tile + rl*512 + ((32*cf + 8*lhi) ^ swz);
          *(unsigned long long*)dst = (unsigned long long)p0 | ((unsigned long long)p1 << 32);
        }
        pacc[g][cf] = (f32x4){0.f,0.f,0.f,0.f};
      }
    }
    if (wrtile){
      asm volatile("s_waitcnt lgkmcnt(0)" ::: "memory");
      __builtin_amdgcn_sched_barrier(0);
    }
  };

  // main loop: 16 weight stages per level (Wg kf0..7, then Wp kf0..7)
#pragma unroll 1
  for (int l=0; l<NL; ++l){
#pragma unroll 1
    for (int q=0; q<16; ++q){
      int s = l*16 + q;
      __syncthreads();                       // stage s resident (vmcnt drained)
      if (s+1 < 128) gstage(s+1, (s+1)&1);   // prefetch next stage (overlaps compute)
      if (q == 8) gate_epi(l);               // gate GEMM done -> sigmoid+stash
      if (q == 0 && l > 0) cand_epi(l-1, true); // finish prev level, rewrite tile
      compute(s);
    }
  }
  cand_epi(NL-1, false);

  // ---- outputs ----
#pragma unroll
  for (int g=0; g<2; ++g){
    int rowg = row0 + rbase + g*16 + llo;
#pragma unroll
    for (int cf=0; cf<8; ++cf){
      F4 o;
#pragma unroll
      for (int j=0;j<4;++j)
        o.a[j] = accv[g][cf][j] + active[g]*ubf(curD[g][2*cf + (j>>1)], j&1);
      *(float4*)&out[(size_t)rowg*ND + 16*cf + 4*lhi] = o.f;
    }
  }
  if (lhi == 0){
    const size_t BD = (size_t)NB*ND;
#pragma unroll
    for (int g=0; g<2; ++g){
      int rowg = row0 + rbase + g*16 + llo;
      out[BD + rowg]                = gsum[g]*(1.0f/NL);
      out[BD + NB + rowg]           = dsum[g]*(1.0f/NL);
      out[BD + 2*(size_t)NB + rowg] = depth[g] + active[g]*(float)NL;
      out[BD + 3*(size_t)NB + rowg] = smass[g];
      out[BD + 4*(size_t)NB + rowg] = asum[g]*(1.0f/NL);
    }
  }
}

extern "C" void kernel_launch(void* const* d_in, const int* in_sizes, int n_in,
                              void* d_out, int out_size, void* d_ws, size_t ws_size,
                              hipStream_t stream){
  const float* signal   = (const float*)d_in[0];
  const float* previous = (const float*)d_in[1];
  const float* Wp    = (const float*)d_in[2];
  const float* bp    = (const float*)d_in[3];
  const float* Wg    = (const float*)d_in[4];
  const float* bg    = (const float*)d_in[5];
  const float* Ws    = (const float*)d_in[6];
  const float* bs    = (const float*)d_in[7];
  const float* gamma = (const float*)d_in[8];
  const float* beta  = (const float*)d_in[9];

  uint4* wpk  = (uint4*)d_ws;                                   // 1 MB packed weights
  float* pdot = (float*)((char*)d_ws + (size_t)NL*2*65536);     // 8 MB prevdot

  repack_w<<<256, 256, 0, stream>>>(Wp, Wg, wpk);
  prevdot_k<<<NB/16, 256, 0, stream>>>(previous, Ws, bs, pdot);
  fused_k<<<NB/128, 256, 0, stream>>>(signal, previous, bp, bg, Ws, gamma, beta,
                                      wpk, pdot, (float*)d_out);
}

// Round 7
// 1060.985 us; speedup vs baseline: 2.1070x; 1.2867x over previous
//
#include <hip/hip_runtime.h>
#include <math.h>

#define NB 262144
#define ND 128
#define NL 8

typedef __bf16 bf16x8 __attribute__((ext_vector_type(8)));
typedef float  f32x4  __attribute__((ext_vector_type(4)));

union BFP { unsigned int u; __bf16 h[2]; unsigned short s[2]; };
union F4  { float4 f; float a[4]; };

__device__ __forceinline__ float sigm(float x){ return 1.0f/(1.0f + __expf(-x)); }
__device__ __forceinline__ float tanhfast(float x){
  float t = __expf(-2.0f*fabsf(x));
  return copysignf((1.0f - t)/(1.0f + t), x);
}
// row-reduction: row r lives in lanes {r, r+16, r+32, r+48}
__device__ __forceinline__ float redrow(float v){
  v += __shfl_xor(v, 16);
  v += __shfl_xor(v, 32);
  return v;
}
__device__ __forceinline__ unsigned int pk2(float a, float b){
  BFP x; x.h[0]=(__bf16)a; x.h[1]=(__bf16)b; return x.u;
}
__device__ __forceinline__ float ubf(unsigned int u, int hi){
  BFP x; x.u = u; return (float)x.h[hi];
}
__device__ __forceinline__ void gload16(const void* g, void* s){
  __builtin_amdgcn_global_load_lds((const __attribute__((address_space(1))) unsigned int*)g,
                                   (__attribute__((address_space(3))) unsigned int*)s,
                                   16, 0, 0);
}

// ---- prep 1: repack Wg/Wp (fp32, [L][256][128]) into bf16 A-operand fragment order ----
// dst: [(l*2+mat)][kf(8)][cf(8)][lane(64)] x 16B ; mat 0 = Wg, 1 = Wp
// frag: n = cf*16 + (lane&15), k = kf*32 + (lane>>4)*8 + j
__global__ void repack_w(const float* __restrict__ Wp, const float* __restrict__ Wg,
                         uint4* __restrict__ dst){
  int t = blockIdx.x*256 + threadIdx.x;      // 65536 threads
  int lane = t & 63;
  int frag = t >> 6;                          // 1024 frags
  int cf = frag & 7, kf = (frag >> 3) & 7, mat = (frag >> 6) & 1, l = frag >> 7;
  const float* W = mat ? Wp : Wg;
  int k = kf*32 + (lane >> 4)*8;
  int n = cf*16 + (lane & 15);
  const float* src = W + (l*256 + k)*ND + n;
  bf16x8 v;
#pragma unroll
  for (int j=0;j<8;++j) v[j] = (__bf16)src[j*ND];
  dst[((l*2 + mat)*64 + kf*8 + cf)*64 + lane] = __builtin_bit_cast(uint4, v);
}

// ---- prep 2: pdot[row][l] = previous[row] . Ws_l[128:256] + bs_l (fp32) ----
__global__ void prevdot_k(const float* __restrict__ previous, const float* __restrict__ Ws,
                          const float* __restrict__ bs, float* __restrict__ pdot){
  int t = blockIdx.x*256 + threadIdx.x;
  int row = t >> 4, g = t & 15;
  const float* p = previous + (size_t)row*ND + g*8;
  float4 a = *(const float4*)p;
  float4 b = *(const float4*)(p+4);
#pragma unroll
  for (int l=0;l<NL;++l){
    const float* w = Ws + l*256 + 128 + g*8;
    float s = a.x*w[0] + a.y*w[1] + a.z*w[2] + a.w*w[3]
            + b.x*w[4] + b.y*w[5] + b.z*w[6] + b.w*w[7];
    s += __shfl_xor(s,1); s += __shfl_xor(s,2); s += __shfl_xor(s,4); s += __shfl_xor(s,8);
    if (g==0) pdot[row*NL + l] = s + bs[l];
  }
}

// ---- main fused kernel: 256 threads, 4 waves x 32 rows (swapped-operand MFMA) ----
// Joined tile [128 rows][256 feats] bf16 (64KB): cur half rewritten per level,
// prev half written once. Weights stream through 2x8KB ping-pong LDS stages.
// LDS 80KB -> exactly 2 blocks/CU = 2 waves/EU; force the allocator to plan
// for that occupancy (256 VGPR budget) instead of its 4-waves/EU default.
__global__ __attribute__((amdgpu_flat_work_group_size(256,256)))
           __attribute__((amdgpu_waves_per_eu(2,2)))
void fused_k(const float* __restrict__ signal, const float* __restrict__ previous,
             const float* __restrict__ bp, const float* __restrict__ bg,
             const float* __restrict__ Ws, const float* __restrict__ gamma,
             const float* __restrict__ beta,
             const uint4* __restrict__ wpk, const float* __restrict__ pdot,
             float* __restrict__ out)
{
  __shared__ unsigned short tile[128*256];   // 64KB joined [row][feat], XOR-swizzled
  __shared__ uint4 wbuf[2][512];             // 2 x 8KB weight stages (1 kf x 8 cf)

  const int tid  = threadIdx.x;
  const int w    = tid >> 6;
  const int lane = tid & 63;
  const int llo  = lane & 15;
  const int lhi  = lane >> 4;
  const int rbase = w * 32;
  const int row0  = blockIdx.x * 128;
  const int swz   = (llo & 7) << 4;

  auto gstage = [&](int s, int b){
    const char* src = (const char*)wpk + (size_t)s*8192;
    char* d = (char*)&wbuf[b][0];
    gload16(src + tid*16, d + tid*16);
    gload16(src + 4096 + tid*16, d + 4096 + tid*16);
  };

  // prologue: start staging level0/Wg/kf0 immediately
  gstage(0, 0);

  // per-lane state: rows r(g) = row0 + rbase + g*16 + llo ; feats n = 16cf+4lhi+j
  unsigned int gstash[2][16];   // gate, bf16 packed
  float accv[2][8][4];          // accumulated output (f32)
  f32x4 pacc[2][8];             // MFMA accumulators / current un values
  float active[2], depth[2], smass[2], gsum[2], dsum[2], asum[2];

#pragma unroll
  for (int g=0; g<2; ++g){
    int rl = rbase + g*16 + llo;
    int rowg = row0 + rl;
    // signal -> tile cur half (D-position addresses)
#pragma unroll
    for (int cf=0; cf<8; ++cf){
      F4 v; v.f = *(const float4*)&signal[(size_t)rowg*ND + 16*cf + 4*lhi];
      unsigned p0 = pk2(v.a[0], v.a[1]);
      unsigned p1 = pk2(v.a[2], v.a[3]);
      char* dst = (char*)tile + rl*512 + ((32*cf + 8*lhi) ^ swz);
      *(unsigned long long*)dst = (unsigned long long)p0 | ((unsigned long long)p1 << 32);
      pacc[g][cf] = (f32x4){0.f,0.f,0.f,0.f};
#pragma unroll
      for (int j=0;j<4;++j) accv[g][cf][j] = 0.f;
    }
    // previous -> tile prev half (feats 128..255), written once
#pragma unroll
    for (int kfp=0; kfp<4; ++kfp){
      const float* p = previous + (size_t)rowg*ND + kfp*32 + lhi*8;
      F4 a; a.f = *(const float4*)p;
      F4 b; b.f = *(const float4*)(p+4);
      uint4 pv;
      pv.x = pk2(a.a[0], a.a[1]);
      pv.y = pk2(a.a[2], a.a[3]);
      pv.z = pk2(b.a[0], b.a[1]);
      pv.w = pk2(b.a[2], b.a[3]);
      char* dst = (char*)tile + rl*512 + ((256 + 64*kfp + 16*lhi) ^ swz);
      *(uint4*)dst = pv;
    }
    active[g]=1.f; depth[g]=0.f; smass[g]=0.f; gsum[g]=0.f; dsum[g]=0.f; asum[g]=0.f;
  }

  auto compute = [&](int s){
    int kf  = s & 7;
    int buf = s & 1;
    int off = (64*kf + 16*lhi) ^ swz;
    const char* tb = (const char*)tile;
    bf16x8 xf0 = __builtin_bit_cast(bf16x8, *(const uint4*)(tb + (rbase      + llo)*512 + off));
    bf16x8 xf1 = __builtin_bit_cast(bf16x8, *(const uint4*)(tb + (rbase + 16 + llo)*512 + off));
    const uint4* wb = &wbuf[buf][lane];
#pragma unroll
    for (int cf=0; cf<8; ++cf){
      bf16x8 wf = __builtin_bit_cast(bf16x8, wb[cf*64]);
      pacc[0][cf] = __builtin_amdgcn_mfma_f32_16x16x32_bf16(wf, xf0, pacc[0][cf], 0,0,0);
      pacc[1][cf] = __builtin_amdgcn_mfma_f32_16x16x32_bf16(wf, xf1, pacc[1][cf], 0,0,0);
    }
  };

  auto gate_epi = [&](int lev){
#pragma unroll
    for (int g=0; g<2; ++g){
      float gp = 0.f;
#pragma unroll
      for (int cf=0; cf<8; ++cf){
        F4 bgv; bgv.f = *(const float4*)&bg[lev*ND + 16*cf + 4*lhi];
        float g0 = sigm(pacc[g][cf][0] + bgv.a[0]);
        float g1 = sigm(pacc[g][cf][1] + bgv.a[1]);
        float g2 = sigm(pacc[g][cf][2] + bgv.a[2]);
        float g3 = sigm(pacc[g][cf][3] + bgv.a[3]);
        gp += g0 + g1 + g2 + g3;
        gstash[g][2*cf]   = pk2(g0, g1);
        gstash[g][2*cf+1] = pk2(g2, g3);
        pacc[g][cf] = (f32x4){0.f,0.f,0.f,0.f};
      }
      gsum[g] += redrow(gp) * (1.0f/ND);
    }
  };

  auto cand_epi = [&](int lev, bool wrtile){
#pragma unroll
    for (int g=0; g<2; ++g){
      int rl = rbase + g*16 + llo;
      int rowg = row0 + rl;
      const char* cbase = (const char*)tile + rl*512;
      float s1 = 0.f, s2 = 0.f;
#pragma unroll
      for (int cf=0; cf<8; ++cf){
        F4 bpv; bpv.f = *(const float4*)&bp[lev*ND + 16*cf + 4*lhi];
        unsigned long long cw = *(const unsigned long long*)(cbase + ((32*cf + 8*lhi) ^ swz));
        unsigned c0 = (unsigned)cw, c1 = (unsigned)(cw >> 32);
#pragma unroll
        for (int j=0;j<4;++j){
          float cand = tanhfast(pacc[g][cf][j] + bpv.a[j]);
          float c  = ubf(j<2 ? c0 : c1, j&1);
          float gt = ubf(gstash[g][2*cf + (j>>1)], j&1);
          float x = c + gt*(cand - c);
          pacc[g][cf][j] = x;
          s1 += x; s2 += x*x;
        }
      }
      s1 = redrow(s1); s2 = redrow(s2);
      float mu  = s1*(1.0f/ND);
      float inv = rsqrtf(s2*(1.0f/ND) - mu*mu + 1e-5f);
      float dp = 0.f, ap = 0.f;
#pragma unroll
      for (int cf=0; cf<8; ++cf){
        F4 gm; gm.f = *(const float4*)&gamma[lev*ND + 16*cf + 4*lhi];
        F4 bt; bt.f = *(const float4*)&beta [lev*ND + 16*cf + 4*lhi];
        F4 wv; wv.f = *(const float4*)&Ws   [lev*2*ND + 16*cf + 4*lhi];
        unsigned long long cw = *(const unsigned long long*)(cbase + ((32*cf + 8*lhi) ^ swz));
        unsigned c0 = (unsigned)cw, c1 = (unsigned)(cw >> 32);
#pragma unroll
        for (int j=0;j<4;++j){
          float un = (pacc[g][cf][j] - mu)*inv*gm.a[j] + bt.a[j];
          float c  = ubf(j<2 ? c0 : c1, j&1);
          float df = un - c;
          dp += df*df;
          ap += un*wv.a[j];
          pacc[g][cf][j] = un;
        }
      }
      dp = redrow(dp); ap = redrow(ap);
      float adq = sigm(ap + pdot[(size_t)rowg*NL + lev]);
      float sp  = sigm((adq - 0.6f)*10.0f);
      float sm  = active[g]*sp;
      asum[g] += adq;
      dsum[g] += sqrtf(dp);
      depth[g] += sm * (float)(lev+1);
      smass[g] += sm;
      active[g] *= (1.0f - sp);
#pragma unroll
      for (int cf=0; cf<8; ++cf){
#pragma unroll
        for (int j=0;j<4;++j) accv[g][cf][j] += sm * pacc[g][cf][j];
        if (wrtile){
          unsigned p0 = pk2(pacc[g][cf][0], pacc[g][cf][1]);
          unsigned p1 = pk2(pacc[g][cf][2], pacc[g][cf][3]);
          char* dst = (char*)tile + rl*512 + ((32*cf + 8*lhi) ^ swz);
          *(unsigned long long*)dst = (unsigned long long)p0 | ((unsigned long long)p1 << 32);
          // pacc must be ZERO before the next level's gate GEMM (r6 bug:
          // leaving un here added LN output into the gate accumulator)
          pacc[g][cf] = (f32x4){0.f,0.f,0.f,0.f};
        }
      }
    }
    if (wrtile){
      asm volatile("s_waitcnt lgkmcnt(0)" ::: "memory");
      __builtin_amdgcn_sched_barrier(0);
    }
  };

  // main loop: 16 weight stages per level (Wg kf0..7, then Wp kf0..7)
#pragma unroll 1
  for (int l=0; l<NL; ++l){
#pragma unroll 1
    for (int q=0; q<16; ++q){
      int s = l*16 + q;
      __syncthreads();                       // stage s resident (vmcnt drained)
      if (s+1 < 128) gstage(s+1, (s+1)&1);   // prefetch next stage (overlaps compute)
      if (q == 8) gate_epi(l);               // gate GEMM done -> sigmoid+stash
      if (q == 0 && l > 0) cand_epi(l-1, true); // finish prev level, rewrite tile
      compute(s);
    }
  }
  cand_epi(NL-1, false);                     // pacc now holds final updated vector

  // ---- outputs ----
#pragma unroll
  for (int g=0; g<2; ++g){
    int rowg = row0 + rbase + g*16 + llo;
#pragma unroll
    for (int cf=0; cf<8; ++cf){
      F4 o;
#pragma unroll
      for (int j=0;j<4;++j)
        o.a[j] = accv[g][cf][j] + active[g]*pacc[g][cf][j];
      *(float4*)&out[(size_t)rowg*ND + 16*cf + 4*lhi] = o.f;
    }
  }
  if (lhi == 0){
    const size_t BD = (size_t)NB*ND;
#pragma unroll
    for (int g=0; g<2; ++g){
      int rowg = row0 + rbase + g*16 + llo;
      out[BD + rowg]                = gsum[g]*(1.0f/NL);
      out[BD + NB + rowg]           = dsum[g]*(1.0f/NL);
      out[BD + 2*(size_t)NB + rowg] = depth[g] + active[g]*(float)NL;
      out[BD + 3*(size_t)NB + rowg] = smass[g];
      out[BD + 4*(size_t)NB + rowg] = asum[g]*(1.0f/NL);
    }
  }
}

extern "C" void kernel_launch(void* const* d_in, const int* in_sizes, int n_in,
                              void* d_out, int out_size, void* d_ws, size_t ws_size,
                              hipStream_t stream){
  const float* signal   = (const float*)d_in[0];
  const float* previous = (const float*)d_in[1];
  const float* Wp    = (const float*)d_in[2];
  const float* bp    = (const float*)d_in[3];
  const float* Wg    = (const float*)d_in[4];
  const float* bg    = (const float*)d_in[5];
  const float* Ws    = (const float*)d_in[6];
  const float* bs    = (const float*)d_in[7];
  const float* gamma = (const float*)d_in[8];
  const float* beta  = (const float*)d_in[9];

  uint4* wpk  = (uint4*)d_ws;                                   // 1 MB packed weights
  float* pdot = (float*)((char*)d_ws + (size_t)NL*2*65536);     // 8 MB prevdot

  repack_w<<<256, 256, 0, stream>>>(Wp, Wg, wpk);
  prevdot_k<<<NB/16, 256, 0, stream>>>(previous, Ws, bs, pdot);
  fused_k<<<NB/128, 256, 0, stream>>>(signal, previous, bp, bg, Ws, gamma, beta,
                                      wpk, pdot, (float*)d_out);
}

// Round 9
// 1045.057 us; speedup vs baseline: 2.1391x; 1.0152x over previous
//
#include <hip/hip_runtime.h>
#include <math.h>

#define NB 262144
#define ND 128
#define NL 8

typedef __bf16 bf16x8 __attribute__((ext_vector_type(8)));
typedef float  f32x4  __attribute__((ext_vector_type(4)));

union BFP { unsigned int u; __bf16 h[2]; unsigned short s[2]; };
union F4  { float4 f; float a[4]; };

__device__ __forceinline__ float sigm(float x){ return 1.0f/(1.0f + __expf(-x)); }
__device__ __forceinline__ float tanhfast(float x){
  float t = __expf(-2.0f*fabsf(x));
  return copysignf((1.0f - t)/(1.0f + t), x);
}
// row r lives in lanes {r, r+16, r+32, r+48}
__device__ __forceinline__ float redrow(float v){
  v += __shfl_xor(v, 16);
  v += __shfl_xor(v, 32);
  return v;
}
__device__ __forceinline__ unsigned int pk2(float a, float b){
  BFP x; x.h[0]=(__bf16)a; x.h[1]=(__bf16)b; return x.u;
}
__device__ __forceinline__ float ubf(unsigned int u, int hi){
  BFP x; x.u = u; return (float)x.h[hi];
}
__device__ __forceinline__ void gload16(const void* g, void* s){
  __builtin_amdgcn_global_load_lds((const __attribute__((address_space(1))) unsigned int*)g,
                                   (__attribute__((address_space(3))) unsigned int*)s,
                                   16, 0, 0);
}

// ---- prep 1: repack Wg/Wp (fp32, [L][256][128]) into bf16 A-operand fragment order ----
// dst: [(l*2+mat)][kf(8)][cf(8)][lane(64)] x 16B ; mat 0 = Wg, 1 = Wp  (r7 verbatim)
__global__ void repack_w(const float* __restrict__ Wp, const float* __restrict__ Wg,
                         uint4* __restrict__ dst){
  int t = blockIdx.x*256 + threadIdx.x;      // 65536 threads
  int lane = t & 63;
  int frag = t >> 6;                          // 1024 frags
  int cf = frag & 7, kf = (frag >> 3) & 7, mat = (frag >> 6) & 1, l = frag >> 7;
  const float* W = mat ? Wp : Wg;
  int k = kf*32 + (lane >> 4)*8;
  int n = cf*16 + (lane & 15);
  const float* src = W + (l*256 + k)*ND + n;
  bf16x8 v;
#pragma unroll
  for (int j=0;j<8;++j) v[j] = (__bf16)src[j*ND];
  dst[((l*2 + mat)*64 + kf*8 + cf)*64 + lane] = __builtin_bit_cast(uint4, v);
}

// ---- prep 2: pdot[row][l] = previous[row] . Ws_l[128:256] + bs_l (r7 verbatim) ----
__global__ void prevdot_k(const float* __restrict__ previous, const float* __restrict__ Ws,
                          const float* __restrict__ bs, float* __restrict__ pdot){
  int t = blockIdx.x*256 + threadIdx.x;
  int row = t >> 4, g = t & 15;
  const float* p = previous + (size_t)row*ND + g*8;
  float4 a = *(const float4*)p;
  float4 b = *(const float4*)(p+4);
#pragma unroll
  for (int l=0;l<NL;++l){
    const float* w = Ws + l*256 + 128 + g*8;
    float s = a.x*w[0] + a.y*w[1] + a.z*w[2] + a.w*w[3]
            + b.x*w[4] + b.y*w[5] + b.z*w[6] + b.w*w[7];
    s += __shfl_xor(s,1); s += __shfl_xor(s,2); s += __shfl_xor(s,4); s += __shfl_xor(s,8);
    if (g==0) pdot[row*NL + l] = s + bs[l];
  }
}

// ---- main fused kernel: 512 threads = 8 waves x 16 rows, r7-proven schedule ----
// Per-thread live state ~105 VGPR -> fits the 128 cap with NO spill, all-fp32.
// Joined tile [128 rows][256 feats] bf16 (64KB), wave-private 16-row slices;
// weights stream through 2 x 8KB ping-pong LDS stages (16 stages/level).
__global__ __launch_bounds__(512)
void fused_k(const float* __restrict__ signal, const float* __restrict__ previous,
             const float* __restrict__ bp, const float* __restrict__ bg,
             const float* __restrict__ Ws, const float* __restrict__ gamma,
             const float* __restrict__ beta,
             const uint4* __restrict__ wpk, const float* __restrict__ pdot,
             float* __restrict__ out)
{
  __shared__ unsigned short tile[128*256];   // 64KB joined [row][feat], XOR-swizzled
  __shared__ uint4 wbuf[2][512];             // 2 x 8KB weight stages (1 kf x 8 cf)

  const int tid  = threadIdx.x;
  const int w    = tid >> 6;                 // 0..7
  const int lane = tid & 63;
  const int llo  = lane & 15;
  const int lhi  = lane >> 4;
  const int rbase = w * 16;
  const int row0  = blockIdx.x * 128;
  const int swz   = (llo & 7) << 4;

  auto gstage = [&](int s, int b){
    // 512 threads x 16B = 8KB stage
    gload16((const char*)wpk + (size_t)s*8192 + tid*16, (char*)&wbuf[b][0] + tid*16);
  };
  gstage(0, 0);                              // prologue prefetch

  // per-lane state: row rl = rbase + llo ; feats n = 16cf+4lhi+j
  unsigned int gstash[16];    // gate, bf16 packed (16 regs)
  float accv[8][4];           // accumulated output, fp32 (32 regs)
  f32x4 pacc[8];              // MFMA acc / x / un (32 regs)
  float active, depth, smass, gsum, dsum, asum;

  {
    int rl = rbase + llo;
    int rowg = row0 + rl;
#pragma unroll
    for (int cf=0; cf<8; ++cf){
      F4 v; v.f = *(const float4*)&signal[(size_t)rowg*ND + 16*cf + 4*lhi];
      unsigned p0 = pk2(v.a[0], v.a[1]);
      unsigned p1 = pk2(v.a[2], v.a[3]);
      char* dst = (char*)tile + rl*512 + ((32*cf + 8*lhi) ^ swz);
      *(unsigned long long*)dst = (unsigned long long)p0 | ((unsigned long long)p1 << 32);
      pacc[cf] = (f32x4){0.f,0.f,0.f,0.f};
#pragma unroll
      for (int j=0;j<4;++j) accv[cf][j] = 0.f;
    }
#pragma unroll
    for (int kfp=0; kfp<4; ++kfp){
      const float* p = previous + (size_t)rowg*ND + kfp*32 + lhi*8;
      F4 a; a.f = *(const float4*)p;
      F4 b; b.f = *(const float4*)(p+4);
      uint4 pv;
      pv.x = pk2(a.a[0], a.a[1]);
      pv.y = pk2(a.a[2], a.a[3]);
      pv.z = pk2(b.a[0], b.a[1]);
      pv.w = pk2(b.a[2], b.a[3]);
      char* dst = (char*)tile + rl*512 + ((256 + 64*kfp + 16*lhi) ^ swz);
      *(uint4*)dst = pv;
    }
    active=1.f; depth=0.f; smass=0.f; gsum=0.f; dsum=0.f; asum=0.f;
  }

  auto compute = [&](int s){
    int kf  = s & 7;
    int buf = s & 1;
    int off = (64*kf + 16*lhi) ^ swz;
    bf16x8 xf = __builtin_bit_cast(bf16x8,
        *(const uint4*)((const char*)tile + (rbase + llo)*512 + off));
    const uint4* wb = &wbuf[buf][lane];
#pragma unroll
    for (int cf=0; cf<8; ++cf){
      bf16x8 wf = __builtin_bit_cast(bf16x8, wb[cf*64]);
      pacc[cf] = __builtin_amdgcn_mfma_f32_16x16x32_bf16(wf, xf, pacc[cf], 0,0,0);
    }
  };

  auto gate_epi = [&](int lev){
    float gp = 0.f;
#pragma unroll
    for (int cf=0; cf<8; ++cf){
      F4 bgv; bgv.f = *(const float4*)&bg[lev*ND + 16*cf + 4*lhi];
      float g0 = sigm(pacc[cf][0] + bgv.a[0]);
      float g1 = sigm(pacc[cf][1] + bgv.a[1]);
      float g2 = sigm(pacc[cf][2] + bgv.a[2]);
      float g3 = sigm(pacc[cf][3] + bgv.a[3]);
      gp += g0 + g1 + g2 + g3;
      gstash[2*cf]   = pk2(g0, g1);
      gstash[2*cf+1] = pk2(g2, g3);
      pacc[cf] = (f32x4){0.f,0.f,0.f,0.f};
    }
    gsum += redrow(gp) * (1.0f/ND);
  };

  auto cand_epi = [&](int lev, bool wr){
    int rl = rbase + llo;
    int rowg = row0 + rl;
    char* cbase = (char*)tile + rl*512;
    float s1 = 0.f, s2 = 0.f;
#pragma unroll
    for (int cf=0; cf<8; ++cf){
      F4 bpv; bpv.f = *(const float4*)&bp[lev*ND + 16*cf + 4*lhi];
      unsigned long long cw = *(const unsigned long long*)(cbase + ((32*cf + 8*lhi) ^ swz));
      unsigned c0 = (unsigned)cw, c1 = (unsigned)(cw >> 32);
#pragma unroll
      for (int j=0;j<4;++j){
        float cand = tanhfast(pacc[cf][j] + bpv.a[j]);
        float cc = ubf(j<2 ? c0 : c1, j&1);
        float gt = ubf(gstash[2*cf + (j>>1)], j&1);
        float x = cc + gt*(cand - cc);
        pacc[cf][j] = x;
        s1 += x; s2 += x*x;
      }
    }
    s1 = redrow(s1); s2 = redrow(s2);
    float mu  = s1*(1.0f/ND);
    float inv = rsqrtf(s2*(1.0f/ND) - mu*mu + 1e-5f);
    float dp = 0.f, ap = 0.f;
#pragma unroll
    for (int cf=0; cf<8; ++cf){
      F4 gm; gm.f = *(const float4*)&gamma[lev*ND + 16*cf + 4*lhi];
      F4 bt; bt.f = *(const float4*)&beta [lev*ND + 16*cf + 4*lhi];
      F4 wv; wv.f = *(const float4*)&Ws   [lev*2*ND + 16*cf + 4*lhi];
      unsigned long long cw = *(const unsigned long long*)(cbase + ((32*cf + 8*lhi) ^ swz));
      unsigned c0 = (unsigned)cw, c1 = (unsigned)(cw >> 32);
#pragma unroll
      for (int j=0;j<4;++j){
        float un = (pacc[cf][j] - mu)*inv*gm.a[j] + bt.a[j];
        float cc = ubf(j<2 ? c0 : c1, j&1);
        float df = un - cc;
        dp += df*df;
        ap += un*wv.a[j];
        pacc[cf][j] = un;
      }
    }
    dp = redrow(dp); ap = redrow(ap);
    float adq = sigm(ap + pdot[(size_t)rowg*NL + lev]);
    float sp  = sigm((adq - 0.6f)*10.0f);
    float sm  = active*sp;
    asum += adq;
    dsum += sqrtf(dp);
    depth += sm * (float)(lev+1);
    smass += sm;
    active *= (1.0f - sp);
#pragma unroll
    for (int cf=0; cf<8; ++cf){
#pragma unroll
      for (int j=0;j<4;++j) accv[cf][j] += sm * pacc[cf][j];
      if (wr){
        unsigned p0 = pk2(pacc[cf][0], pacc[cf][1]);
        unsigned p1 = pk2(pacc[cf][2], pacc[cf][3]);
        char* dst = cbase + ((32*cf + 8*lhi) ^ swz);
        *(unsigned long long*)dst = (unsigned long long)p0 | ((unsigned long long)p1 << 32);
        // pacc must be ZERO before the next level's gate GEMM
        pacc[cf] = (f32x4){0.f,0.f,0.f,0.f};
      }
    }
    if (wr){
      asm volatile("s_waitcnt lgkmcnt(0)" ::: "memory");
      __builtin_amdgcn_sched_barrier(0);
    }
  };

  // main loop: 16 weight stages per level (Wg kf0..7, then Wp kf0..7) — r7 schedule
#pragma unroll 1
  for (int l=0; l<NL; ++l){
#pragma unroll 1
    for (int q=0; q<16; ++q){
      int s = l*16 + q;
      __syncthreads();                       // stage s resident (vmcnt drained)
      if (s+1 < 128) gstage(s+1, (s+1)&1);   // prefetch next stage
      if (q == 8) gate_epi(l);               // gate GEMM done -> sigmoid+stash
      if (q == 0 && l > 0) cand_epi(l-1, true); // finish prev level, rewrite tile
      compute(s);
    }
  }
  cand_epi(NL-1, false);                     // pacc now holds final updated vector

  // ---- outputs ----
  {
    int rowg = row0 + rbase + llo;
#pragma unroll
    for (int cf=0; cf<8; ++cf){
      F4 o;
#pragma unroll
      for (int j=0;j<4;++j)
        o.a[j] = accv[cf][j] + active*pacc[cf][j];
      *(float4*)&out[(size_t)rowg*ND + 16*cf + 4*lhi] = o.f;
    }
    if (lhi == 0){
      const size_t BD = (size_t)NB*ND;
      out[BD + rowg]                = gsum*(1.0f/NL);
      out[BD + NB + rowg]           = dsum*(1.0f/NL);
      out[BD + 2*(size_t)NB + rowg] = depth + active*(float)NL;
      out[BD + 3*(size_t)NB + rowg] = smass;
      out[BD + 4*(size_t)NB + rowg] = asum*(1.0f/NL);
    }
  }
}

extern "C" void kernel_launch(void* const* d_in, const int* in_sizes, int n_in,
                              void* d_out, int out_size, void* d_ws, size_t ws_size,
                              hipStream_t stream){
  const float* signal   = (const float*)d_in[0];
  const float* previous = (const float*)d_in[1];
  const float* Wp    = (const float*)d_in[2];
  const float* bp    = (const float*)d_in[3];
  const float* Wg    = (const float*)d_in[4];
  const float* bg    = (const float*)d_in[5];
  const float* Ws    = (const float*)d_in[6];
  const float* bs    = (const float*)d_in[7];
  const float* gamma = (const float*)d_in[8];
  const float* beta  = (const float*)d_in[9];

  uint4* wpk  = (uint4*)d_ws;                                   // 1 MB packed weights
  float* pdot = (float*)((char*)d_ws + (size_t)NL*2*65536);     // 8 MB prevdot [row][l]

  repack_w<<<256, 256, 0, stream>>>(Wp, Wg, wpk);
  prevdot_k<<<NB/16, 256, 0, stream>>>(previous, Ws, bs, pdot);
  fused_k<<<NB/128, 512, 0, stream>>>(signal, previous, bp, bg, Ws, gamma, beta,
                                      wpk, pdot, (float*)d_out);
}